// Round 5
// baseline (118.399 us; speedup 1.0000x reference)
//
#include <hip/hip_runtime.h>

#define NB 64
#define NN 1500
#define NM 100
#define NBINS 1280
#define KEEP 128

#define NROWS (NB*NN)          // 96000 output rows
#define DELTA_FLOATS 31104000u // floats in delta section
#define ROWQ 81                // quads per row (deltas); floats per row (labels)

// ws layout: 0: lbl[96000] int (384000 B) | 384000: d4[96000] float4 (1536000 B)

// ---------------- K1: per-batch IoU + counting top-128 select -> per-row table ----------------
__global__ __launch_bounds__(256) void k1_select(
    const float4* __restrict__ roi, const float4* __restrict__ gt,
    const int* __restrict__ gtl, const int* __restrict__ rpos,
    const int* __restrict__ rneg,
    int* __restrict__ lbl, float4* __restrict__ d4)
{
    __shared__ float4 gtb[NM];
    __shared__ float  gta[NM];
    __shared__ short  sc[2][NN];
    __shared__ unsigned char kp[2][NN];
    __shared__ short  bestS[NN];
    __shared__ int    hist[NBINS];
    __shared__ int    partial[256];
    __shared__ int    wcnt[4];
    __shared__ int    carry;
    __shared__ int    sstar_s, q_s;

    int b = blockIdx.x;
    int tid = threadIdx.x;

    if (tid < NM) {
        float4 g = gt[b*NM + tid];
        gtb[tid] = g;
        gta[tid] = (g.z - g.x) * (g.w - g.y);
    }
    __syncthreads();
    for (int c = 0; c < 6; ++c) {
        int n = c*256 + tid;
        if (n < NN) {
            int idx = b*NN + n;
            float4 r = roi[idx];                   // [y1,x1,y2,x2]
            float by1=r.x, bx1=r.y, by2=r.z, bx2=r.w;
            float barea = (by2-by1)*(bx2-bx1);
            float bestIoU = -1.0f; int bestIdx = 0;
            for (int m = 0; m < NM; ++m) {
                float4 g = gtb[m];
                float xt = fmaxf(bx1, g.y);
                float yt = fmaxf(by1, g.x);
                float xb = fminf(bx2, g.w);
                float yb = fminf(by2, g.z);
                float inter = fmaxf(xb-xt, 0.0f) * fmaxf(yb-yt, 0.0f);
                float uni = (barea + gta[m]) - inter;
                float iou = inter / uni;
                if (iou > bestIoU) { bestIoU = iou; bestIdx = m; } // first-max argmax
            }
            bestS[n] = (short)bestIdx;
            sc[0][n] = (short)((bestIoU > 0.5f) ? rpos[idx] : 0);
            sc[1][n] = (short)((bestIoU < 0.5f && bestIoU > 0.1f) ? rneg[idx] : 0);
        }
    }
    __syncthreads();

    // counting top-128 select (identical logic to passing versions)
    for (int m = 0; m < 2; ++m) {
        for (int s = tid; s < NBINS; s += 256) hist[s] = 0;
        if (tid == 0) { sstar_s = 0; q_s = 0; carry = 0; }
        __syncthreads();
        for (int i = tid; i < NN; i += 256) {
            int s = sc[m][i];
            if (s > 0) atomicAdd(&hist[s], 1);
        }
        __syncthreads();
        int base = tid*5;
        int p = hist[base]+hist[base+1]+hist[base+2]+hist[base+3]+hist[base+4];
        partial[tid] = p;
        __syncthreads();
        int myp = p;
        for (int off = 1; off < 256; off <<= 1) {
            int v = (tid + off < 256) ? partial[tid+off] : 0;
            __syncthreads();
            partial[tid] += v;
            __syncthreads();
        }
        int running = partial[tid] - myp;   // count strictly above my bins
        for (int s = base+4; s >= base; --s) {
            int c = hist[s];
            if (s >= 1 && c > 0 && running < KEEP && running + c >= KEEP) {
                sstar_s = s; q_s = KEEP - running;     // straddle bin
            }
            running += c;
        }
        __syncthreads();
        int sstar = sstar_s, q = q_s;
        for (int c0 = 0; c0 < 6; ++c0) {   // ordered ballot-scan on ties
            int i = c0*256 + tid;
            int s = (i < NN) ? (int)sc[m][i] : 0;
            bool eq = (s > 0) && (s == sstar);
            unsigned long long bal = __ballot(eq);
            int lane = tid & 63, w = tid >> 6;
            if (lane == 0) wcnt[w] = (int)__popcll(bal);
            __syncthreads();
            int pre = carry;
            for (int ww = 0; ww < w; ++ww) pre += wcnt[ww];
            int E = pre + (int)__popcll(bal & ((1ull << lane) - 1ull));
            bool keep = (i < NN) && (s > 0) && (s > sstar || (eq && E < q));
            if (i < NN) kp[m][i] = keep ? 1 : 0;
            __syncthreads();
            if (tid == 0) carry += wcnt[0]+wcnt[1]+wcnt[2]+wcnt[3];
            __syncthreads();
        }
    }
    __syncthreads();

    // per-row table: lab (-1 none / 0 neg / gt label pos) + delta quad value
    for (int i = tid; i < NN; i += 256) {
        int idx = b*NN + i;
        int lab = -1;
        float4 dd = make_float4(0.f,0.f,0.f,0.f);
        if (kp[0][i]) {
            int bi = bestS[i];
            lab = gtl[b*NM + bi];
            float4 r = roi[idx];
            float4 g = gtb[bi];
            float bw = r.w - r.y, bh = r.z - r.x;
            float bcx = r.y + 0.5f*bw, bcy = r.x + 0.5f*bh;
            float gw = g.w - g.y, gh = g.z - g.x;
            float gcx = g.y + 0.5f*gw, gcy = g.x + 0.5f*gh;
            if (bw == 0.0f) bw = 0.001f;
            if (bh == 0.0f) bh = 0.001f;
            float dx  = (gw==0.0f) ? 0.0f : (gcx-bcx)/bw;
            float dy  = (gh==0.0f) ? 0.0f : (gcy-bcy)/bh;
            float dwv = (gw==0.0f) ? 0.0f : logf(gw/bw);
            float dhv = (gh==0.0f) ? 0.0f : logf(gh/bh);
            dd = make_float4(dy/0.1f, dx/0.1f, dhv/0.2f, dwv/0.2f);
        } else if (kp[1][i]) {
            lab = 0;            // one-hot at 0, deltas zero
        }
        lbl[idx] = lab;
        d4[idx] = dd;
    }
}

// ---------------- K2: row-owning writer — zeros + sparse values in one pass ----------------
// Each block owns 64 consecutive rows; each wave 16 rows. Per row: 81 delta quads
// (value dd at slot lab) + 81 label floats (1.0f at slot lab). No cross-block ordering.
__global__ __launch_bounds__(256) void k2_rowfill(
    const int* __restrict__ lbl, const float4* __restrict__ d4,
    float* __restrict__ out)
{
    int tid  = threadIdx.x;
    int lane = tid & 63;
    int wid  = tid >> 6;
    int row0 = blockIdx.x * 64 + wid * 16;
    float4* outq = (float4*)out;
    const float4 z = make_float4(0.f,0.f,0.f,0.f);

    #pragma unroll 4
    for (int k = 0; k < 16; ++k) {
        int r = row0 + k;
        int lab = lbl[r];
        float4 dd = d4[r];
        unsigned int qb = (unsigned int)r * 81u;
        // deltas: quads 0..63 then 64..80
        outq[qb + lane] = (lane == lab) ? dd : z;
        if (lane < 17) outq[qb + 64 + lane] = ((lane + 64) == lab) ? dd : z;
        // labels: floats 0..63 then 64..80
        out[DELTA_FLOATS + qb + lane] = (lane == lab) ? 1.0f : 0.0f;
        if (lane < 17) out[DELTA_FLOATS + qb + 64 + lane] = ((lane + 64) == lab) ? 1.0f : 0.0f;
    }
}

extern "C" void kernel_launch(void* const* d_in, const int* in_sizes, int n_in,
                              void* d_out, int out_size, void* d_ws, size_t ws_size,
                              hipStream_t stream) {
    const float4* roi = (const float4*)d_in[0];   // [B,N,4] f32
    const float4* gt  = (const float4*)d_in[1];   // [B,M,4] f32
    const int* gtl  = (const int*)d_in[2];        // [B,M]
    const int* rpos = (const int*)d_in[3];        // [B,N]
    const int* rneg = (const int*)d_in[4];        // [B,N]
    float* out = (float*)d_out;

    char* ws = (char*)d_ws;
    int*    lbl = (int*)(ws);                // 384000 B
    float4* d4  = (float4*)(ws + 384000);    // 1536000 B

    k1_select <<<NB, 256, 0, stream>>>(roi, gt, gtl, rpos, rneg, lbl, d4);
    k2_rowfill<<<NROWS/64, 256, 0, stream>>>(lbl, d4, out);
}

// Round 6
// 43.190 us; speedup vs baseline: 2.7413x; 2.7413x over previous
//
#include <hip/hip_runtime.h>

#define NB 64
#define NN 1500
#define NM 100
#define NBINS 1280
#define KEEP 128

#define TOTALQ 9720000u        // float4 quads in out (38,880,000 floats / 4)
#define DELTA_FLOATS 31104000u
#define IOU_BLOCKS 384
#define GRID_TOTAL 2048

// ws layout: 0 spos[96000] | 384000 sneg[96000] | 768000 best[96000]  (ints)

// ---------------- K1: fused IoU (blocks 0..383) + zero-fill (blocks 384..2047) ----------------
// (byte-identical to the 44.5 µs passing version)
__global__ __launch_bounds__(256) void k1_fused(
    const float4* __restrict__ roi, const float4* __restrict__ gt,
    const int* __restrict__ rpos, const int* __restrict__ rneg,
    int* __restrict__ spos, int* __restrict__ sneg, int* __restrict__ best,
    float4* __restrict__ outq)
{
    int blk = blockIdx.x;
    int tid = threadIdx.x;
    if (blk < IOU_BLOCKS) {
        __shared__ float4 gtb[NM];
        __shared__ float  gta[NM];
        int b = blk / 6;
        int chunk = blk % 6;
        if (tid < NM) {
            float4 g = gt[b*NM + tid];
            gtb[tid] = g;
            gta[tid] = (g.z - g.x) * (g.w - g.y);
        }
        __syncthreads();
        int n = chunk*256 + tid;
        if (n >= NN) return;
        int idx = b*NN + n;
        float4 r = roi[idx];                        // [y1,x1,y2,x2]
        float by1=r.x, bx1=r.y, by2=r.z, bx2=r.w;
        float barea = (by2-by1)*(bx2-bx1);
        float bestIoU = -1.0f; int bestIdx = 0;
        for (int m = 0; m < NM; ++m) {
            float4 g = gtb[m];
            float xt = fmaxf(bx1, g.y);
            float yt = fmaxf(by1, g.x);
            float xb = fminf(bx2, g.w);
            float yb = fminf(by2, g.z);
            float inter = fmaxf(xb-xt, 0.0f) * fmaxf(yb-yt, 0.0f);
            float uni = (barea + gta[m]) - inter;
            float iou = inter / uni;
            if (iou > bestIoU) { bestIoU = iou; bestIdx = m; }  // first-max argmax
        }
        best[idx] = bestIdx;
        spos[idx] = (bestIoU > 0.5f) ? rpos[idx] : 0;
        sneg[idx] = (bestIoU < 0.5f && bestIoU > 0.1f) ? rneg[idx] : 0;
        return;
    }
    unsigned int t = (unsigned int)(blk - IOU_BLOCKS) * 256u + (unsigned int)tid;
    const unsigned int stride = (GRID_TOTAL - IOU_BLOCKS) * 256u;
    const float4 z = make_float4(0.f, 0.f, 0.f, 0.f);
    for (unsigned int q = t; q < TOTALQ; q += stride) outq[q] = z;
}

// ---------------- K2: barrier-light counting top-128 select + sparse scatter ----------------
__global__ __launch_bounds__(256) void k2_select(
    const float4* __restrict__ roi, const float4* __restrict__ gt,
    const int* __restrict__ gtl,
    const int* __restrict__ spos, const int* __restrict__ sneg,
    const int* __restrict__ best,
    float* __restrict__ out)
{
    __shared__ float4 gtb[NM];
    __shared__ short  sc[2][NN];
    __shared__ unsigned char kp[2][NN];
    __shared__ int    hist[NBINS];
    __shared__ int    waveTot[4];
    __shared__ int    cnt6[6][4];
    __shared__ int    sstar_s, q_s;

    int b = blockIdx.x;
    int tid = threadIdx.x;
    int lane = tid & 63, w = tid >> 6;

    if (tid < NM) gtb[tid] = gt[b*NM + tid];
    for (int i = tid; i < NN; i += 256) {
        sc[0][i] = (short)spos[b*NN+i];
        sc[1][i] = (short)sneg[b*NN+i];
    }
    __syncthreads();

    for (int m = 0; m < 2; ++m) {
        // zero histogram + init straddle result (one barrier window)
        for (int s = tid; s < NBINS; s += 256) hist[s] = 0;
        if (tid == 0) { sstar_s = 0; q_s = 0; }
        __syncthreads();
        for (int i = tid; i < NN; i += 256) {
            int s = sc[m][i];
            if (s > 0) atomicAdd(&hist[s], 1);
        }
        __syncthreads();
        // per-thread sum over 5 bins, wave-level shuffle suffix scan (no barriers),
        // cross-wave combine via 4-entry table (1 barrier)
        int base = tid*5;
        int p = hist[base]+hist[base+1]+hist[base+2]+hist[base+3]+hist[base+4];
        int myp = p;
        #pragma unroll
        for (int off = 1; off < 64; off <<= 1) {
            int v = __shfl_down(p, off, 64);
            if (lane + off < 64) p += v;
        }
        if (lane == 0) waveTot[w] = p;
        __syncthreads();
        int suffix = p;
        for (int ww = w+1; ww < 4; ++ww) suffix += waveTot[ww];
        int running = suffix - myp;          // count in bins strictly above my range
        for (int s = base+4; s >= base; --s) {
            int c = hist[s];
            if (s >= 1 && c > 0 && running < KEEP && running + c >= KEEP) {
                sstar_s = s; q_s = KEEP - running;    // unique straddle bin
            }
            running += c;
        }
        __syncthreads();
        int sstar = sstar_s, q = q_s;

        // ordered tie-scan, two passes, 1 barrier between
        bool eqReg[6];
        int  lowReg[6];
        #pragma unroll
        for (int c = 0; c < 6; ++c) {
            int i = c*256 + tid;
            int s = (i < NN) ? (int)sc[m][i] : 0;
            bool eq = (s > 0) && (s == sstar);
            unsigned long long bal = __ballot(eq);
            if (lane == 0) cnt6[c][w] = (int)__popcll(bal);
            eqReg[c]  = eq;
            lowReg[c] = (int)__popcll(bal & ((1ull << lane) - 1ull));
        }
        __syncthreads();
        int cum = 0;
        #pragma unroll
        for (int c = 0; c < 6; ++c) {
            int preC = cum;
            for (int ww = 0; ww < w; ++ww) preC += cnt6[c][ww];
            int E = preC + lowReg[c];       // global index-order rank among ties
            int i = c*256 + tid;
            if (i < NN) {
                int s = (int)sc[m][i];
                bool keep = (s > 0) && (s > sstar || (eqReg[c] && E < q));
                kp[m][i] = keep ? 1 : 0;
            }
            cum += cnt6[c][0]+cnt6[c][1]+cnt6[c][2]+cnt6[c][3];
        }
        __syncthreads();   // kp ready; protects sstar_s/hist for next mask
    }

    // sparse scatter into the (already zero-filled) output — same as passing version
    for (int i = tid; i < NN; i += 256) {
        int idx = b*NN + i;
        if (kp[0][i]) {
            int bi = best[idx];
            int lab = gtl[b*NM + bi];
            float4 r = roi[idx];
            float4 g = gtb[bi];
            float bw = r.w - r.y, bh = r.z - r.x;
            float bcx = r.y + 0.5f*bw, bcy = r.x + 0.5f*bh;
            float gw = g.w - g.y, gh = g.z - g.x;
            float gcx = g.y + 0.5f*gw, gcy = g.x + 0.5f*gh;
            if (bw == 0.0f) bw = 0.001f;
            if (bh == 0.0f) bh = 0.001f;
            float dx  = (gw==0.0f) ? 0.0f : (gcx-bcx)/bw;
            float dy  = (gh==0.0f) ? 0.0f : (gcy-bcy)/bh;
            float dwv = (gw==0.0f) ? 0.0f : logf(gw/bw);
            float dhv = (gh==0.0f) ? 0.0f : logf(gh/bh);
            float4 dd = make_float4(dy/0.1f, dx/0.1f, dhv/0.2f, dwv/0.2f);
            unsigned int slot = (unsigned int)idx * 81u + (unsigned int)lab;
            reinterpret_cast<float4*>(out)[slot] = dd;     // delta quad
            out[DELTA_FLOATS + slot] = 1.0f;               // one-hot label
        } else if (kp[1][i]) {
            out[DELTA_FLOATS + (unsigned int)idx * 81u] = 1.0f;  // label 0
        }
    }
}

extern "C" void kernel_launch(void* const* d_in, const int* in_sizes, int n_in,
                              void* d_out, int out_size, void* d_ws, size_t ws_size,
                              hipStream_t stream) {
    const float4* roi = (const float4*)d_in[0];   // [B,N,4] f32
    const float4* gt  = (const float4*)d_in[1];   // [B,M,4] f32
    const int* gtl  = (const int*)d_in[2];        // [B,M]
    const int* rpos = (const int*)d_in[3];        // [B,N]
    const int* rneg = (const int*)d_in[4];        // [B,N]
    float* out = (float*)d_out;

    char* ws = (char*)d_ws;
    int* spos = (int*)(ws);               // 384000 B
    int* sneg = (int*)(ws +  384000);     // 384000 B
    int* best = (int*)(ws +  768000);     // 384000 B

    k1_fused <<<GRID_TOTAL, 256, 0, stream>>>(roi, gt, rpos, rneg, spos, sneg, best,
                                              (float4*)out);
    k2_select<<<NB, 256, 0, stream>>>(roi, gt, gtl, spos, sneg, best, out);
}